// Round 4
// baseline (244.855 us; speedup 1.0000x reference)
//
#include <hip/hip_runtime.h>
#include <hip/hip_cooperative_groups.h>
#include <math.h>
#include <stdint.h>

namespace cg = cooperative_groups;

#define NIMG 8
#define HH 1024
#define WW 1024
#define NPIX (HH*WW)
#define PAIRS 10000
#define STRIP 8
#define NSTRIPS 128           // strips per image
#define S1BLOCKS 40           // sample blocks per image (40*256 = 10240 >= PAIRS)
#define NBLK (S1BLOCKS*NIMG)  // 320 blocks total
#define WSLOTS (S1BLOCKS*4)   // per-wave partial slots per image (160)

// ws layout (floats; every slot plainly overwritten each launch — no init):
// [OFF_EDGE .. +NIMG*NSTRIPS)  per-strip squared-sobel max
// [OFF_MD   .. +NIMG*WSLOTS)   per-wave maxdiff partials
// [OFF_LOSS .. +NIMG*WSLOTS)   per-wave loss partials (eq+uneq)
// [OFF_CNT  .. +NIMG*WSLOTS)   per-wave valid-count partials
#define OFF_EDGE 0
#define OFF_MD   1024
#define OFF_LOSS 2304
#define OFF_CNT  3584

__device__ __forceinline__ uint64_t mix64(uint64_t x){
    x += 0x9E3779B97F4A7C15ull;
    x = (x ^ (x >> 30)) * 0xBF58476D1CE4E5B9ull;
    x = (x ^ (x >> 27)) * 0x94D049BB133111EBull;
    return x ^ (x >> 31);
}

__device__ __forceinline__ float block_reduce_max(float v, float* sm){
    for (int off = 32; off; off >>= 1)
        v = fmaxf(v, __shfl_down(v, off));
    int wv = threadIdx.x >> 6, lane = threadIdx.x & 63;
    if (lane == 0) sm[wv] = v;
    __syncthreads();
    if (threadIdx.x == 0){
        float m = fmaxf(fmaxf(sm[0], sm[1]), fmaxf(sm[2], sm[3]));
        sm[0] = m;
    }
    __syncthreads();
    float r = sm[0];
    __syncthreads();
    return r;
}

__device__ __forceinline__ float block_reduce_sum(float v, float* sm){
    for (int off = 32; off; off >>= 1)
        v += __shfl_down(v, off);
    int wv = threadIdx.x >> 6, lane = threadIdx.x & 63;
    if (lane == 0) sm[wv] = v;
    __syncthreads();
    if (threadIdx.x == 0)
        sm[0] = sm[0] + sm[1] + sm[2] + sm[3];
    __syncthreads();
    float r = sm[0];
    __syncthreads();
    return r;
}

__device__ __forceinline__ void sobel_at(const float* __restrict__ x, int r, int c,
                                         float& gx, float& gy){
    const float* p0 = x + (size_t)(r-1)*WW + c;
    const float* p1 = x + (size_t)r*WW + c;
    const float* p2 = x + (size_t)(r+1)*WW + c;
    float a = p0[-1], b = p0[0], cc = p0[1];
    float d = p1[-1],             e = p1[1];
    float f = p2[-1], g = p2[0], h = p2[1];
    gx = (cc - a) + 2.0f*(e - d) + (h - f);
    gy = (a + 2.0f*b + cc) - (f + 2.0f*g + h);
}

__device__ __forceinline__ void load16(const float* __restrict__ p, float* d){
    const float4* q = (const float4*)p;
    float4 v0 = q[0], v1 = q[1], v2 = q[2], v3 = q[3];
    d[0]=v0.x; d[1]=v0.y; d[2]=v0.z; d[3]=v0.w;
    d[4]=v1.x; d[5]=v1.y; d[6]=v1.z; d[7]=v1.w;
    d[8]=v2.x; d[9]=v2.y; d[10]=v2.z; d[11]=v2.w;
    d[12]=v3.x; d[13]=v3.y; d[14]=v3.z; d[15]=v3.w;
}

struct Sample {
    int valid;
    int rowc[4], colc[4];
};

__device__ __forceinline__ Sample draw_sample(int img, int j,
        const float* __restrict__ x, const float* __restrict__ tgt,
        const float* __restrict__ dgt, float thr2){
    Sample s;
    s.valid = 0;
    #pragma unroll
    for (int k = 0; k < 4; ++k){ s.rowc[k] = 0; s.colc[k] = 0; }

    uint64_t base = ((uint64_t)(img * PAIRS + j)) << 10;
    bool pdir = (mix64(((uint64_t)(NIMG * PAIRS + img)) << 10) & 1ull) != 0ull;

    int sh = -1, sw = -1;
    float gxs = 0.0f, gys = 0.0f, e2s = 1.0f;
    for (int att = 0; att < 900; ++att){
        uint64_t u = mix64(base + (uint64_t)att);
        uint32_t pix = (uint32_t)(u >> 44);           // 20-bit uniform
        int r = (int)(pix >> 10);
        int c = (int)(pix & (WW - 1));
        if (r == 0 || r >= HH-1 || c == 0 || c >= WW-1) continue;
        float gx, gy;
        sobel_at(x, r, c, gx, gy);
        float e2 = gx*gx + gy*gy;
        if (!(e2 >= thr2)) continue;
        float dg = dgt[r*WW + c];
        float tg = tgt[r*WW + c];
        if (!(dg > -0.001f && dg < 80.0f && tg != 80.0f)) continue;
        sh = r; sw = c; gxs = gx; gys = gy; e2s = e2;
        break;
    }
    if (sh < 0) return s;

    // cos(theta)=gx/e, sin(theta)=gy/e ; pdir=false: cmul=-cos, rmul=sin
    float inv = rsqrtf(e2s);
    float cmul = gxs * inv;
    float rmul = gys * inv;
    if (!pdir) cmul = -cmul;

    uint64_t u0 = mix64(base + 1000ull);
    uint64_t u1 = mix64(base + 1001ull);
    float dist[4];
    dist[0] = -(float)(2u + (uint32_t)(u0 & 0xFFFFFFFFull) % 29u);
    dist[1] = -(float)(2u + (uint32_t)(u0 >> 32) % 29u);
    dist[2] =  (float)(2u + (uint32_t)(u1 & 0xFFFFFFFFull) % 29u);
    dist[3] =  (float)(2u + (uint32_t)(u1 >> 32) % 29u);

    bool valid = true;
    #pragma unroll
    for (int k = 0; k < 4; ++k){
        int cc2 = sw + (int)rintf(dist[k] * cmul);
        int rr2 = sh + (int)rintf(dist[k] * rmul);
        if (cc2 < 0 || cc2 > WW-1 || rr2 < 0 || rr2 > HH-1) valid = false;
        s.colc[k] = min(max(cc2, 0), WW-1);
        s.rowc[k] = min(max(rr2, 0), HH-1);
    }
    s.valid = valid ? 1 : 0;
    return s;
}

__global__ __launch_bounds__(256, 2) void fused_kernel(
        const float* __restrict__ inputs,
        const float* __restrict__ targets,
        const float* __restrict__ images,
        const float* __restrict__ depth_gt,
        float* __restrict__ ws,
        float* __restrict__ out){
    cg::grid_group grid = cg::this_grid();
    __shared__ float sred[4];
    int tid  = threadIdx.x;
    int wv   = tid >> 6;
    int lane = tid & 63;

    // ---- Phase A: edgemax (strip-rolling sobel, squared magnitude) ----
    {
        int gw = blockIdx.x * 4 + wv;                  // global wave id
        if (gw < NIMG * NSTRIPS){
            int img = gw >> 7, strip = gw & 127;
            const float* x = images + (size_t)img * 3 * NPIX;  // channel 0
            int r0 = 1 + strip * STRIP;
            int r1 = min(r0 + STRIP - 1, HH - 2);
            int c0 = lane * 16;

            float a[16], b[16], n[16];
            load16(x + (size_t)(r0-1)*WW + c0, a);
            load16(x + (size_t)r0*WW + c0, b);
            float m = 0.0f;
            for (int r = r0; r <= r1; ++r){
                load16(x + (size_t)(r+1)*WW + c0, n);
                float sx[16], dy[16];
                #pragma unroll
                for (int i = 0; i < 16; ++i){
                    sx[i] = a[i] + 2.0f*b[i] + n[i];
                    dy[i] = a[i] - n[i];
                }
                float sxl = __shfl_up(sx[15], 1);
                float sxr = __shfl_down(sx[0], 1);
                float dyl = __shfl_up(dy[15], 1);
                float dyr = __shfl_down(dy[0], 1);
                #pragma unroll
                for (int jj = 0; jj < 16; ++jj){
                    float sl = (jj == 0)  ? sxl : sx[jj-1];
                    float sr = (jj == 15) ? sxr : sx[jj+1];
                    float dl = (jj == 0)  ? dyl : dy[jj-1];
                    float dr = (jj == 15) ? dyr : dy[jj+1];
                    float gx = sr - sl;
                    float gy = dl + 2.0f*dy[jj] + dr;
                    float e2 = gx*gx + gy*gy;
                    int c = c0 + jj;
                    if (c >= 1 && c <= WW-2) m = fmaxf(m, e2);
                }
                #pragma unroll
                for (int i = 0; i < 16; ++i){ a[i] = b[i]; b[i] = n[i]; }
            }
            for (int off = 32; off; off >>= 1)
                m = fmaxf(m, __shfl_down(m, off));
            if (lane == 0)
                ws[OFF_EDGE + img * NSTRIPS + strip] = m;
        }
    }
    __threadfence();
    grid.sync();

    // ---- Phase B: sample + classify (pair data stays in registers) ----
    int img = blockIdx.x / S1BLOCKS;
    int jb  = blockIdx.x % S1BLOCKS;
    int j   = jb * 256 + tid;
    const float* x   = images   + (size_t)img * 3 * NPIX;
    const float* inp = inputs   + (size_t)img * NPIX;
    const float* tgt = targets  + (size_t)img * NPIX;
    const float* dgt = depth_gt + (size_t)img * NPIX;

    float ev = 0.0f;
    if (tid < NSTRIPS) ev = ws[OFF_EDGE + img * NSTRIPS + tid];
    float thr2 = 0.01f * block_reduce_max(ev, sred);

    float mdiff = 0.0f, cnt = 0.0f, un = 0.0f;
    float d2[3] = {0.f, 0.f, 0.f};
    float ad[3] = {0.f, 0.f, 0.f};

    if (j < PAIRS){
        Sample s = draw_sample(img, j, x, tgt, dgt, thr2);
        if (s.valid){
            float t4[4], i4[4];
            #pragma unroll
            for (int k = 0; k < 4; ++k){
                int p = s.rowc[k]*WW + s.colc[k];
                t4[k] = tgt[p];
                i4[k] = inp[p];
            }
            #pragma unroll
            for (int k = 0; k < 3; ++k){
                float tA = t4[k], tB = t4[k+1];
                float ratio = (tA + 1e-6f) / (tB + 1e-6f);
                float adk = fabsf(tA - tB);
                mdiff = fmaxf(mdiff, adk);
                bool eq = (ratio < 1.03f) && (ratio > 0.9708737864077669f);
                if (eq){
                    float d = i4[k] - i4[k+1];
                    d2[k] = d*d; ad[k] = adk;
                } else {
                    float lab = (ratio >= 1.03f) ? 1.0f : -1.0f;
                    un += log1pf(expf((i4[k+1] - i4[k]) * lab));
                }
            }
            cnt = 3.0f;
        }
    }

    {
        float m = mdiff;
        for (int off = 32; off; off >>= 1)
            m = fmaxf(m, __shfl_down(m, off));
        if (lane == 0)
            ws[OFF_MD + img * WSLOTS + jb*4 + wv] = m;
    }
    __threadfence();
    grid.sync();

    // ---- Phase C: maxdiff reduce + finish loss from registers ----
    {
        float mv = 0.0f;
        if (tid < WSLOTS) mv = ws[OFF_MD + img * WSLOTS + tid];
        float md = block_reduce_max(mv, sred);
        float inv = 1.0f / (md + 1e-6f);
        float lossv = un
                    + d2[0] * expf(-ad[0] * inv)
                    + d2[1] * expf(-ad[1] * inv)
                    + d2[2] * expf(-ad[2] * inv);
        float c_ = cnt;
        for (int off = 32; off; off >>= 1){
            lossv += __shfl_down(lossv, off);
            c_    += __shfl_down(c_, off);
        }
        if (lane == 0){
            ws[OFF_LOSS + img * WSLOTS + jb*4 + wv] = lossv;
            ws[OFF_CNT  + img * WSLOTS + jb*4 + wv] = c_;
        }
    }
    __threadfence();
    grid.sync();

    // ---- Phase D: final cross-image reduce (block 0) ----
    if (blockIdx.x == 0){
        float tl = 0.0f, tc = 0.0f;
        for (int im = 0; im < NIMG; ++im){
            float l = 0.0f, c = 0.0f;
            if (tid < WSLOTS){
                l = ws[OFF_LOSS + im * WSLOTS + tid];
                c = ws[OFF_CNT  + im * WSLOTS + tid];
            }
            float ls = block_reduce_sum(l, sred);
            float cs = block_reduce_sum(c, sred);
            tl += ls / fmaxf(cs, 1.0f);   // ALPHA = 1
            tc += cs;
        }
        if (tid == 0){
            out[0] = tl / (float)NIMG;
            out[1] = tc / (float)NIMG;
        }
    }
}

extern "C" void kernel_launch(void* const* d_in, const int* in_sizes, int n_in,
                              void* d_out, int out_size, void* d_ws, size_t ws_size,
                              hipStream_t stream) {
    const float* inputs  = (const float*)d_in[0];
    const float* targets = (const float*)d_in[1];
    const float* images  = (const float*)d_in[2];
    const float* depth   = (const float*)d_in[3];
    float* out = (float*)d_out;
    float* ws  = (float*)d_ws;

    void* args[] = { (void*)&inputs, (void*)&targets, (void*)&images,
                     (void*)&depth, (void*)&ws, (void*)&out };
    hipLaunchCooperativeKernel((const void*)fused_kernel, dim3(NBLK), dim3(256),
                               args, 0, stream);
}

// Round 5
// 61.585 us; speedup vs baseline: 3.9759x; 3.9759x over previous
//
#include <hip/hip_runtime.h>
#include <math.h>
#include <stdint.h>

#define NIMG 8
#define HH 1024
#define WW 1024
#define NPIX (HH*WW)
#define PAIRS 10000
#define STRIP 4
#define NSTRIPS 256          // strips per image (rows 1..1022, 4 rows each)
#define S1BLOCKS 40          // sample blocks per image
#define WSLOTS (S1BLOCKS*4)  // per-wave partial slots per image (160)

// ws layout (floats; every slot plainly overwritten each launch — no init):
// [OFF_EDGE .. +NIMG*NSTRIPS)  per-strip squared-sobel max          (2048)
// [OFF_MD   .. +NIMG*WSLOTS)   per-wave maxdiff partials            (1280)
// [OFF_RES  .. +16)            per-image {loss, cnt}
// byte 65536:                  recsA [NIMG*PAIRS] float4 (d2_0,d2_1,d2_2,un)
// byte 65536+NIMG*PAIRS*16:    recsB [NIMG*PAIRS] float4 (ad_0,ad_1,ad_2,cnt)
#define OFF_EDGE 0
#define OFF_MD   2048
#define OFF_RES  3328

__device__ __forceinline__ uint64_t mix64(uint64_t x){
    x += 0x9E3779B97F4A7C15ull;
    x = (x ^ (x >> 30)) * 0xBF58476D1CE4E5B9ull;
    x = (x ^ (x >> 27)) * 0x94D049BB133111EBull;
    return x ^ (x >> 31);
}

__device__ __forceinline__ float block_reduce_max(float v, float* sm){
    for (int off = 32; off; off >>= 1)
        v = fmaxf(v, __shfl_down(v, off));
    int wv = threadIdx.x >> 6, lane = threadIdx.x & 63;
    if (lane == 0) sm[wv] = v;
    __syncthreads();
    if (threadIdx.x == 0)
        sm[0] = fmaxf(fmaxf(sm[0], sm[1]), fmaxf(sm[2], sm[3]));
    __syncthreads();
    float r = sm[0];
    __syncthreads();
    return r;
}

__device__ __forceinline__ float block_reduce_sum(float v, float* sm){
    for (int off = 32; off; off >>= 1)
        v += __shfl_down(v, off);
    int wv = threadIdx.x >> 6, lane = threadIdx.x & 63;
    if (lane == 0) sm[wv] = v;
    __syncthreads();
    if (threadIdx.x == 0)
        sm[0] = sm[0] + sm[1] + sm[2] + sm[3];
    __syncthreads();
    float r = sm[0];
    __syncthreads();
    return r;
}

__device__ __forceinline__ void sobel_at(const float* __restrict__ x, int r, int c,
                                         float& gx, float& gy){
    const float* p0 = x + (size_t)(r-1)*WW + c;
    const float* p1 = x + (size_t)r*WW + c;
    const float* p2 = x + (size_t)(r+1)*WW + c;
    float a = p0[-1], b = p0[0], cc = p0[1];
    float d = p1[-1],             e = p1[1];
    float f = p2[-1], g = p2[0], h = p2[1];
    gx = (cc - a) + 2.0f*(e - d) + (h - f);
    gy = (a + 2.0f*b + cc) - (f + 2.0f*g + h);
}

__device__ __forceinline__ void load16(const float* __restrict__ p, float* d){
    const float4* q = (const float4*)p;
    float4 v0 = q[0], v1 = q[1], v2 = q[2], v3 = q[3];
    d[0]=v0.x; d[1]=v0.y; d[2]=v0.z; d[3]=v0.w;
    d[4]=v1.x; d[5]=v1.y; d[6]=v1.z; d[7]=v1.w;
    d[8]=v2.x; d[9]=v2.y; d[10]=v2.z; d[11]=v2.w;
    d[12]=v3.x; d[13]=v3.y; d[14]=v3.z; d[15]=v3.w;
}

// One wave owns a 1024-wide row span (16 cols/lane), rolls 3 rows in registers,
// separable sobel, cross-lane neighbors via shuffles, max of SQUARED magnitude.
__global__ __launch_bounds__(256) void edgemax_kernel(const float* __restrict__ images,
                                                      float* __restrict__ edgepart){
    int img  = blockIdx.y;
    const float* x = images + (size_t)img * 3 * NPIX;   // channel 0
    int wv   = threadIdx.x >> 6;
    int lane = threadIdx.x & 63;
    int strip = blockIdx.x * 4 + wv;                    // 0..255
    int r0 = 1 + strip * STRIP;
    int r1 = min(r0 + STRIP - 1, HH - 2);
    int c0 = lane * 16;

    float a[16], b[16], n[16];
    load16(x + (size_t)(r0-1)*WW + c0, a);
    load16(x + (size_t)r0*WW + c0, b);

    float m = 0.0f;
    for (int r = r0; r <= r1; ++r){
        load16(x + (size_t)(r+1)*WW + c0, n);
        float sx[16], dy[16];
        #pragma unroll
        for (int i = 0; i < 16; ++i){
            sx[i] = a[i] + 2.0f*b[i] + n[i];
            dy[i] = a[i] - n[i];
        }
        float sxl = __shfl_up(sx[15], 1);
        float sxr = __shfl_down(sx[0], 1);
        float dyl = __shfl_up(dy[15], 1);
        float dyr = __shfl_down(dy[0], 1);
        #pragma unroll
        for (int j = 0; j < 16; ++j){
            float sl = (j == 0)  ? sxl : sx[j-1];
            float sr = (j == 15) ? sxr : sx[j+1];
            float dl = (j == 0)  ? dyl : dy[j-1];
            float dr = (j == 15) ? dyr : dy[j+1];
            float gx = sr - sl;
            float gy = dl + 2.0f*dy[j] + dr;
            float e2 = gx*gx + gy*gy;
            int c = c0 + j;
            if (c >= 1 && c <= WW-2) m = fmaxf(m, e2);
        }
        #pragma unroll
        for (int i = 0; i < 16; ++i){ a[i] = b[i]; b[i] = n[i]; }
    }
    for (int off = 32; off; off >>= 1)
        m = fmaxf(m, __shfl_down(m, off));
    if (lane == 0)
        edgepart[img * NSTRIPS + strip] = m;
}

struct Cand {
    int pass;
    int r, c;
    float gx, gy, e2;
};

// Unconditional clamped loads -> full ILP; pass iff in-border && edge && mask.
__device__ __forceinline__ Cand eval_cand(uint64_t u,
        const float* __restrict__ x, const float* __restrict__ tgt,
        const float* __restrict__ dgt, float thr2){
    Cand s;
    uint32_t pix = (uint32_t)(u >> 44);               // 20-bit uniform
    s.r = (int)(pix >> 10);
    s.c = (int)(pix & (WW - 1));
    int rl = min(max(s.r, 1), HH-2);
    int cl = min(max(s.c, 1), WW-2);
    sobel_at(x, rl, cl, s.gx, s.gy);
    s.e2 = s.gx*s.gx + s.gy*s.gy;
    float dg = dgt[rl*WW + cl];
    float tg = tgt[rl*WW + cl];
    s.pass = (s.r == rl) && (s.c == cl) && (s.e2 >= thr2) &&
             (dg > -0.001f && dg < 80.0f && tg != 80.0f);
    return s;
}

__global__ __launch_bounds__(256) void sample_kernel(
                               const float* __restrict__ inputs,
                               const float* __restrict__ targets,
                               const float* __restrict__ images,
                               const float* __restrict__ depth_gt,
                               float* __restrict__ ws,
                               float4* __restrict__ recsA,
                               float4* __restrict__ recsB){
    __shared__ float sred[4];
    int img = blockIdx.y;
    int jb  = blockIdx.x;
    int tid = threadIdx.x;
    int j   = jb * 256 + tid;
    const float* x   = images   + (size_t)img * 3 * NPIX;
    const float* inp = inputs   + (size_t)img * NPIX;
    const float* tgt = targets  + (size_t)img * NPIX;
    const float* dgt = depth_gt + (size_t)img * NPIX;

    float ev = 0.0f;
    if (tid < NSTRIPS) ev = ws[OFF_EDGE + img * NSTRIPS + tid];
    float thr2 = 0.01f * block_reduce_max(ev, sred);

    float mdiff = 0.0f;
    float4 recA = make_float4(0.f, 0.f, 0.f, 0.f);   // d2[3], un
    float4 recB = make_float4(0.f, 0.f, 0.f, 0.f);   // ad[3], cnt

    if (j < PAIRS){
        uint64_t base = ((uint64_t)(img * PAIRS + j)) << 10;
        bool pdir = (mix64(((uint64_t)(NIMG * PAIRS + img)) << 10) & 1ull) != 0ull;

        // attempts 0 and 1 evaluated in parallel (ILP); same selection order.
        Cand c0 = eval_cand(mix64(base + 0ull), x, tgt, dgt, thr2);
        Cand c1 = eval_cand(mix64(base + 1ull), x, tgt, dgt, thr2);
        Cand sel;
        int found = 0;
        if (c0.pass){ sel = c0; found = 1; }
        else if (c1.pass){ sel = c1; found = 1; }
        else {
            for (int att = 2; att < 900; ++att){
                Cand ck = eval_cand(mix64(base + (uint64_t)att), x, tgt, dgt, thr2);
                if (ck.pass){ sel = ck; found = 1; break; }
            }
        }

        if (found){
            float inv = rsqrtf(sel.e2);
            float cmul = sel.gx * inv;
            float rmul = sel.gy * inv;
            if (!pdir) cmul = -cmul;

            uint64_t u0 = mix64(base + 1000ull);
            uint64_t u1 = mix64(base + 1001ull);
            float dist[4];
            dist[0] = -(float)(2u + (uint32_t)(u0 & 0xFFFFFFFFull) % 29u);
            dist[1] = -(float)(2u + (uint32_t)(u0 >> 32) % 29u);
            dist[2] =  (float)(2u + (uint32_t)(u1 & 0xFFFFFFFFull) % 29u);
            dist[3] =  (float)(2u + (uint32_t)(u1 >> 32) % 29u);

            int rowc[4], colc[4];
            bool valid = true;
            #pragma unroll
            for (int k = 0; k < 4; ++k){
                int cc2 = sel.c + (int)rintf(dist[k] * cmul);
                int rr2 = sel.r + (int)rintf(dist[k] * rmul);
                if (cc2 < 0 || cc2 > WW-1 || rr2 < 0 || rr2 > HH-1) valid = false;
                colc[k] = min(max(cc2, 0), WW-1);
                rowc[k] = min(max(rr2, 0), HH-1);
            }

            if (valid){
                float t4[4], i4[4];
                #pragma unroll
                for (int k = 0; k < 4; ++k){
                    int p = rowc[k]*WW + colc[k];
                    t4[k] = tgt[p];
                    i4[k] = inp[p];
                }
                float d2a[3], ada[3];
                float un = 0.0f;
                #pragma unroll
                for (int k = 0; k < 3; ++k){
                    float tA = t4[k], tB = t4[k+1];
                    float ratio = (tA + 1e-6f) / (tB + 1e-6f);
                    float adk = fabsf(tA - tB);
                    mdiff = fmaxf(mdiff, adk);
                    bool eq = (ratio < 1.03f) && (ratio > 0.9708737864077669f);
                    if (eq){
                        float d = i4[k] - i4[k+1];
                        d2a[k] = d*d; ada[k] = adk;
                    } else {
                        d2a[k] = 0.f; ada[k] = 0.f;
                        float lab = (ratio >= 1.03f) ? 1.0f : -1.0f;
                        un += log1pf(expf((i4[k+1] - i4[k]) * lab));
                    }
                }
                recA = make_float4(d2a[0], d2a[1], d2a[2], un);
                recB = make_float4(ada[0], ada[1], ada[2], 3.0f);
            }
        }
        recsA[img * PAIRS + j] = recA;
        recsB[img * PAIRS + j] = recB;
    }

    for (int off = 32; off; off >>= 1)
        mdiff = fmaxf(mdiff, __shfl_down(mdiff, off));
    if ((tid & 63) == 0)
        ws[OFF_MD + img * WSLOTS + jb*4 + (tid >> 6)] = mdiff;
}

// One block per image: reduce maxdiff partials, scan records, finish loss.
__global__ __launch_bounds__(256) void finish_kernel(
                               float* __restrict__ ws,
                               const float4* __restrict__ recsA,
                               const float4* __restrict__ recsB){
    __shared__ float sred[4];
    int img = blockIdx.x;
    int tid = threadIdx.x;

    float mv = 0.0f;
    if (tid < WSLOTS) mv = ws[OFF_MD + img * WSLOTS + tid];
    float md = block_reduce_max(mv, sred);
    float inv = 1.0f / (md + 1e-6f);

    float loss = 0.0f, cnt = 0.0f;
    for (int r = tid; r < PAIRS; r += 256){
        float4 A = recsA[img * PAIRS + r];
        float4 B = recsB[img * PAIRS + r];
        loss += A.w
              + A.x * expf(-B.x * inv)
              + A.y * expf(-B.y * inv)
              + A.z * expf(-B.z * inv);
        cnt  += B.w;
    }
    loss = block_reduce_sum(loss, sred);
    cnt  = block_reduce_sum(cnt, sred);
    if (tid == 0){
        ws[OFF_RES + img*2 + 0] = loss;
        ws[OFF_RES + img*2 + 1] = cnt;
    }
}

__global__ void finalize_kernel(const float* __restrict__ ws,
                                float* __restrict__ out){
    if (threadIdx.x == 0){
        float tl = 0.0f, tc = 0.0f;
        for (int i = 0; i < NIMG; ++i){
            float loss = ws[OFF_RES + i*2 + 0];
            float cnt  = ws[OFF_RES + i*2 + 1];
            tl += loss / fmaxf(cnt, 1.0f);   // ALPHA = 1
            tc += cnt;
        }
        out[0] = tl / (float)NIMG;
        out[1] = tc / (float)NIMG;
    }
}

extern "C" void kernel_launch(void* const* d_in, const int* in_sizes, int n_in,
                              void* d_out, int out_size, void* d_ws, size_t ws_size,
                              hipStream_t stream) {
    const float* inputs  = (const float*)d_in[0];
    const float* targets = (const float*)d_in[1];
    const float* images  = (const float*)d_in[2];
    const float* depth   = (const float*)d_in[3];
    float* out = (float*)d_out;

    float* ws    = (float*)d_ws;
    float4* recsA = (float4*)((char*)d_ws + 65536);
    float4* recsB = recsA + (size_t)NIMG * PAIRS;

    hipLaunchKernelGGL(edgemax_kernel, dim3(NSTRIPS/4, NIMG), dim3(256), 0, stream,
                       images, ws + OFF_EDGE);
    hipLaunchKernelGGL(sample_kernel, dim3(S1BLOCKS, NIMG), dim3(256), 0, stream,
                       inputs, targets, images, depth, ws, recsA, recsB);
    hipLaunchKernelGGL(finish_kernel, dim3(NIMG), dim3(256), 0, stream,
                       ws, recsA, recsB);
    hipLaunchKernelGGL(finalize_kernel, dim3(1), dim3(64), 0, stream, ws, out);
}